// Round 4
// baseline (744.489 us; speedup 1.0000x reference)
//
#include <hip/hip_runtime.h>
#include <hip/hip_fp16.h>

#define N_NODES 100000
#define N_EDGES 1600000
#define N_GRAPHS 512
#define FEAT 128
#define EMB 32
#define ZROW N_NODES                        // dedicated zero row in hs tables
#define NCOPY 64                            // privatized pool accumulator copies
#define NBKT 1000                           // dst buckets (100 nodes each)
#define NPB 100                             // nodes per bucket
#define LDSW 33                             // padded LDS row stride (words)
#define ABLK 512                            // bin phase blocks (512 keeps cnt/boff at 2MB)
#define EPB 3125                            // ceil(N_EDGES / ABLK)
#define NTILE (N_NODES / 16)                // 6250 MFMA row tiles
#define SENT ((u32)ZROW * (u32)NPB)         // sentinel edge -> zero row, local dst 0

typedef unsigned short u16;
typedef unsigned int u32;
typedef _Float16 f16;
typedef float f32x4 __attribute__((ext_vector_type(4)));
typedef unsigned short u16x4 __attribute__((ext_vector_type(4)));
typedef f16 f16x8 __attribute__((ext_vector_type(8)));

__device__ __forceinline__ float4 h4_to_f4(u16x4 v) {
  union { unsigned int u; __half2 h; } a, b;
  a.u = (unsigned int)v.x | ((unsigned int)v.y << 16);
  b.u = (unsigned int)v.z | ((unsigned int)v.w << 16);
  float2 f0 = __half22float2(a.h);
  float2 f1 = __half22float2(b.h);
  return make_float4(f0.x, f0.y, f1.x, f1.y);
}

__device__ __forceinline__ u16x4 f4_to_h4(float4 f) {
  union { unsigned int u; __half2 h; } a, b;
  a.h = __float22half2_rn(make_float2(f.x, f.y));
  b.h = __float22half2_rn(make_float2(f.z, f.w));
  u16x4 r;
  r.x = (u16)(a.u & 0xffff); r.y = (u16)(a.u >> 16);
  r.z = (u16)(b.u & 0xffff); r.w = (u16)(b.u >> 16);
  return r;
}

__device__ __forceinline__ float4 relu_row(float4 acc, float d, float4 bq) {
  float4 o;
  o.x = fmaxf(fmaf(acc.x, d, bq.x), 0.f);
  o.y = fmaxf(fmaf(acc.y, d, bq.y), 0.f);
  o.z = fmaxf(fmaf(acc.z, d, bq.z), 0.f);
  o.w = fmaxf(fmaf(acc.w, d, bq.w), 0.f);
  return o;
}

// ---------------- misc ----------------

__global__ __launch_bounds__(512) void k_gcnt(const int* __restrict__ batch,
                                              int* __restrict__ gcnt) {
  __shared__ int first[N_GRAPHS + 1];
  int g = threadIdx.x;
  int lo = 0, hi = N_NODES;
  while (lo < hi) {
    int mid = (lo + hi) >> 1;
    if (batch[mid] < g) lo = mid + 1; else hi = mid;
  }
  first[g] = lo;
  if (g == 0) first[N_GRAPHS] = N_NODES;
  __syncthreads();
  gcnt[g] = first[g + 1] - first[g];
}

// ---------------- binned edge partition (dst buckets of 100 nodes) ----------------

__global__ __launch_bounds__(256) void k_binA(const int* __restrict__ dst,
                                              int* __restrict__ cnt) {
  __shared__ int h[NBKT];
  int k = blockIdx.x, t = threadIdx.x;
  for (int i = t; i < NBKT; i += 256) h[i] = 0;
  __syncthreads();
  int e0 = k * EPB;
  int e1 = min(e0 + EPB, N_EDGES);
  for (int e = e0 + t; e < e1; e += 256)
    atomicAdd(&h[(u32)dst[e] / (u32)NPB], 1);
  __syncthreads();
  for (int i = t; i < NBKT; i += 256) cnt[k * NBKT + i] = h[i];
}

// per-bucket exclusive scan over the ABLK=512 block counts (2 per thread)
__global__ __launch_bounds__(256) void k_binscanA(const int* __restrict__ cnt,
                                                  int* __restrict__ off,
                                                  int* __restrict__ tot) {
  __shared__ int sh[256];
  int b = blockIdx.x, t = threadIdx.x;
  int v[2];
#pragma unroll
  for (int j = 0; j < 2; j++) v[j] = cnt[(t * 2 + j) * NBKT + b];
  int tsum = v[0] + v[1];
  sh[t] = tsum;
  __syncthreads();
  for (int o = 1; o < 256; o <<= 1) {
    int add = (t >= o) ? sh[t - o] : 0;
    __syncthreads();
    sh[t] += add;
    __syncthreads();
  }
  int p = sh[t] - tsum;
#pragma unroll
  for (int j = 0; j < 2; j++) {
    off[(t * 2 + j) * NBKT + b] = p;
    p += v[j];
  }
  if (t == 255) tot[b] = p;
}

// exclusive scan over NBKT=1000 bucket totals (4 per thread)
__global__ __launch_bounds__(256) void k_binscanB(const int* __restrict__ tot,
                                                  int* __restrict__ base) {
  __shared__ int sh[256];
  int t = threadIdx.x;
  int v[4];
#pragma unroll
  for (int j = 0; j < 4; j++) {
    int i = t * 4 + j;
    v[j] = (i < NBKT) ? tot[i] : 0;
  }
  int tsum = v[0] + v[1] + v[2] + v[3];
  sh[t] = tsum;
  __syncthreads();
  for (int o = 1; o < 256; o <<= 1) {
    int add = (t >= o) ? sh[t - o] : 0;
    __syncthreads();
    sh[t] += add;
    __syncthreads();
  }
  int p = sh[t] - tsum;
#pragma unroll
  for (int j = 0; j < 4; j++) {
    int i = t * 4 + j;
    if (i < NBKT) base[i] = p;
    p += v[j];
  }
  if (t == 255) base[NBKT] = p;
}

__global__ __launch_bounds__(256) void k_binscat(const int* __restrict__ src,
                                                 const int* __restrict__ dst,
                                                 const int* __restrict__ off,
                                                 const int* __restrict__ base,
                                                 u32* __restrict__ binbuf) {
  __shared__ int posB[NBKT];
  __shared__ int h[NBKT];
  int k = blockIdx.x, t = threadIdx.x;
  for (int i = t; i < NBKT; i += 256) {
    posB[i] = base[i] + off[k * NBKT + i];
    h[i] = 0;
  }
  __syncthreads();
  int e0 = k * EPB;
  int e1 = min(e0 + EPB, N_EDGES);
  for (int e = e0 + t; e < e1; e += 256) {
    u32 d = (u32)dst[e];
    int b = d / (u32)NPB;
    int r = atomicAdd(&h[b], 1);
    binbuf[posB[b] + r] = (u32)src[e] * (u32)NPB + (d - (u32)b * NPB);
  }
}

// degree -> dis = rsqrt(deg+1), fused; also zeroes the hs ZROW once
__global__ __launch_bounds__(256) void k_deg_dis(const u32* __restrict__ binbuf,
                                                 const int* __restrict__ base,
                                                 float* __restrict__ dis,
                                                 u16* __restrict__ hs1) {
  __shared__ int c[NPB];
  int b = blockIdx.x, t = threadIdx.x;
  for (int i = t; i < NPB; i += 256) c[i] = 0;
  __syncthreads();
  int s0 = base[b], s1 = base[b + 1];
  for (int i = s0 + t; i < s1; i += 256) {
    u32 p = __builtin_nontemporal_load(&binbuf[i]);
    u32 s = p / (u32)NPB;
    atomicAdd(&c[p - s * (u32)NPB], 1);
  }
  __syncthreads();
  for (int i = t; i < NPB; i += 256)
    dis[b * NPB + i] = rsqrtf((float)c[i] + 1.0f);
  if (b == 0)
    for (int i = t; i < EMB; i += 256) hs1[(size_t)ZROW * EMB + i] = 0;
}

// ---------------- GEMMs via MFMA 16x16x32 f16 (W in register B-frags) ----------------

__global__ __launch_bounds__(256) void k_gemm1(const float* __restrict__ x,
                                               const float* __restrict__ W1,
                                               const float* __restrict__ dis,
                                               u16* __restrict__ hs1) {
  int wid = (blockIdx.x * 256 + threadIdx.x) >> 6;   // wave id = 16-row tile
  if (wid >= NTILE) return;
  int l = threadIdx.x & 63;
  int m = l & 15, q = l >> 4;
  f16x8 B[4][2];
#pragma unroll
  for (int s = 0; s < 4; ++s)
#pragma unroll
    for (int h = 0; h < 2; ++h)
#pragma unroll
      for (int j = 0; j < 8; ++j)
        B[s][h][j] = (f16)W1[(s * 32 + q * 8 + j) * EMB + h * 16 + m];
  int row = wid * 16 + m;
  const float* xr = x + (size_t)row * FEAT + q * 8;
  f32x4 acc0 = {0.f, 0.f, 0.f, 0.f}, acc1 = {0.f, 0.f, 0.f, 0.f};
#pragma unroll
  for (int s = 0; s < 4; ++s) {
    f32x4 xa = __builtin_nontemporal_load((const f32x4*)(xr + s * 32));
    f32x4 xb = __builtin_nontemporal_load((const f32x4*)(xr + s * 32 + 4));
    f16x8 A;
    A[0] = (f16)xa.x; A[1] = (f16)xa.y; A[2] = (f16)xa.z; A[3] = (f16)xa.w;
    A[4] = (f16)xb.x; A[5] = (f16)xb.y; A[6] = (f16)xb.z; A[7] = (f16)xb.w;
    acc0 = __builtin_amdgcn_mfma_f32_16x16x32_f16(A, B[s][0], acc0, 0, 0, 0);
    acc1 = __builtin_amdgcn_mfma_f32_16x16x32_f16(A, B[s][1], acc1, 0, 0, 0);
  }
  f32x4 dq = *(const f32x4*)(dis + wid * 16 + q * 4);
  u16* o = hs1 + (size_t)(wid * 16) * EMB;
#pragma unroll
  for (int i = 0; i < 4; ++i) {
    int r = q * 4 + i;
    float dv = (i == 0) ? dq.x : (i == 1) ? dq.y : (i == 2) ? dq.z : dq.w;
    o[(size_t)r * EMB + m]      = __half_as_ushort(__float2half_rn(acc0[i] * dv));
    o[(size_t)r * EMB + 16 + m] = __half_as_ushort(__float2half_rn(acc1[i] * dv));
  }
}

__global__ __launch_bounds__(256) void k_gemm2(const u16* __restrict__ in1,
                                               const float* __restrict__ W2,
                                               const float* __restrict__ dis,
                                               u16* __restrict__ hs2) {
  int wid = (blockIdx.x * 256 + threadIdx.x) >> 6;
  if (wid >= NTILE) return;
  int l = threadIdx.x & 63;
  int m = l & 15, q = l >> 4;
  f16x8 B[2];
#pragma unroll
  for (int h = 0; h < 2; ++h)
#pragma unroll
    for (int j = 0; j < 8; ++j)
      B[h][j] = (f16)W2[(q * 8 + j) * EMB + h * 16 + m];
  int row = wid * 16 + m;
  f16x8 A = *(const f16x8*)(in1 + (size_t)row * EMB + q * 8);
  f32x4 acc0 = {0.f, 0.f, 0.f, 0.f}, acc1 = {0.f, 0.f, 0.f, 0.f};
  acc0 = __builtin_amdgcn_mfma_f32_16x16x32_f16(A, B[0], acc0, 0, 0, 0);
  acc1 = __builtin_amdgcn_mfma_f32_16x16x32_f16(A, B[1], acc1, 0, 0, 0);
  f32x4 dq = *(const f32x4*)(dis + wid * 16 + q * 4);
  u16* o = hs2 + (size_t)(wid * 16) * EMB;
#pragma unroll
  for (int i = 0; i < 4; ++i) {
    int r = q * 4 + i;
    float dv = (i == 0) ? dq.x : (i == 1) ? dq.y : (i == 2) ? dq.z : dq.w;
    o[(size_t)r * EMB + m]      = __half_as_ushort(__float2half_rn(acc0[i] * dv));
    o[(size_t)r * EMB + 16 + m] = __half_as_ushort(__float2half_rn(acc1[i] * dv));
  }
}

// ---------------- Aggregation: bucket-LDS scatter-add (no CSR) ----------------
// Block = 100-node dst bucket; edges read straight from binbuf. 8-lane group per
// edge gathers the 64B hs[src] row and ds_add_f32's into a padded LDS accumulator
// (fire-and-forget -> nothing waits on the atomic). 4 edges in flight per group
// (sentinel SENT -> zero row, harmless add to acc[0]). 13.2KB LDS -> 8 blocks/CU
// -> full occupancy. Deletes the entire CSR build (scans, fillB, col, pad8).

__device__ __forceinline__ void agg_edges(float (*acc)[LDSW],
                                          const u16x4* __restrict__ t4,
                                          const u32* __restrict__ binbuf,
                                          int eb, int ee, int G, int sub) {
  for (int e = eb + G; e < ee; e += 128) {
    u32 p0 = __builtin_nontemporal_load(&binbuf[e]);
    u32 p1 = (e + 32 < ee) ? __builtin_nontemporal_load(&binbuf[e + 32]) : SENT;
    u32 p2 = (e + 64 < ee) ? __builtin_nontemporal_load(&binbuf[e + 64]) : SENT;
    u32 p3 = (e + 96 < ee) ? __builtin_nontemporal_load(&binbuf[e + 96]) : SENT;
    u32 q0 = p0 / (u32)NPB; int l0 = (int)(p0 - q0 * NPB);
    u32 q1 = p1 / (u32)NPB; int l1 = (int)(p1 - q1 * NPB);
    u32 q2 = p2 / (u32)NPB; int l2 = (int)(p2 - q2 * NPB);
    u32 q3 = p3 / (u32)NPB; int l3 = (int)(p3 - q3 * NPB);
    u16x4 v0 = t4[(size_t)q0 * 8 + sub];
    u16x4 v1 = t4[(size_t)q1 * 8 + sub];
    u16x4 v2 = t4[(size_t)q2 * 8 + sub];
    u16x4 v3 = t4[(size_t)q3 * 8 + sub];
    float4 f0 = h4_to_f4(v0), f1 = h4_to_f4(v1);
    float4 f2 = h4_to_f4(v2), f3 = h4_to_f4(v3);
    float* a0 = &acc[l0][sub * 4];
    float* a1 = &acc[l1][sub * 4];
    float* a2 = &acc[l2][sub * 4];
    float* a3 = &acc[l3][sub * 4];
    atomicAdd(a0 + 0, f0.x); atomicAdd(a0 + 1, f0.y);
    atomicAdd(a0 + 2, f0.z); atomicAdd(a0 + 3, f0.w);
    atomicAdd(a1 + 0, f1.x); atomicAdd(a1 + 1, f1.y);
    atomicAdd(a1 + 2, f1.z); atomicAdd(a1 + 3, f1.w);
    atomicAdd(a2 + 0, f2.x); atomicAdd(a2 + 1, f2.y);
    atomicAdd(a2 + 2, f2.z); atomicAdd(a2 + 3, f2.w);
    atomicAdd(a3 + 0, f3.x); atomicAdd(a3 + 1, f3.y);
    atomicAdd(a3 + 2, f3.z); atomicAdd(a3 + 3, f3.w);
  }
}

__global__ __launch_bounds__(256) void k_agg1(const u16* __restrict__ hs,
                                              const u32* __restrict__ binbuf,
                                              const int* __restrict__ base,
                                              const float* __restrict__ dis,
                                              const float* __restrict__ b,
                                              u16* __restrict__ out) {
  __shared__ float acc[NPB][LDSW];
  int t = threadIdx.x, bkt = blockIdx.x;
  for (int i = t; i < NPB * LDSW; i += 256) ((float*)acc)[i] = 0.f;
  __syncthreads();
  const u16x4* t4 = (const u16x4*)hs;
  agg_edges(acc, t4, binbuf, base[bkt], base[bkt + 1], t >> 3, t & 7);
  __syncthreads();
  for (int idx = t; idx < NPB * 8; idx += 256) {
    int ld = idx >> 3, sb = idx & 7;
    int node = bkt * NPB + ld;
    float4 sv = h4_to_f4(t4[(size_t)node * 8 + sb]);
    const float* ap = &acc[ld][sb * 4];
    float4 A = make_float4(ap[0] + sv.x, ap[1] + sv.y, ap[2] + sv.z, ap[3] + sv.w);
    float4 bq = ((const float4*)b)[sb];
    float4 o = relu_row(A, dis[node], bq);
    ((u16x4*)(out + (size_t)node * EMB))[sb] = f4_to_h4(o);
  }
}

__global__ __launch_bounds__(256) void k_agg2pool(const u16* __restrict__ hs,
                                                  const u32* __restrict__ binbuf,
                                                  const int* __restrict__ base,
                                                  const float* __restrict__ dis,
                                                  const float* __restrict__ b2,
                                                  const float* __restrict__ Wo,
                                                  const int* __restrict__ batch,
                                                  float* __restrict__ gaccP) {
  __shared__ float acc[NPB][LDSW];
  int t = threadIdx.x, bkt = blockIdx.x;
  for (int i = t; i < NPB * LDSW; i += 256) ((float*)acc)[i] = 0.f;
  __syncthreads();
  const u16x4* t4 = (const u16x4*)hs;
  agg_edges(acc, t4, binbuf, base[bkt], base[bkt + 1], t >> 3, t & 7);
  __syncthreads();
  for (int idx = t; idx < NPB * 8; idx += 256) {
    int ld = idx >> 3, sb = idx & 7;
    int node = bkt * NPB + ld;
    float4 sv = h4_to_f4(t4[(size_t)node * 8 + sb]);
    const float* ap = &acc[ld][sb * 4];
    float4 A = make_float4(ap[0] + sv.x, ap[1] + sv.y, ap[2] + sv.z, ap[3] + sv.w);
    float4 bq = ((const float4*)b2)[sb];
    float4 wq = ((const float4*)Wo)[sb];
    float4 o = relu_row(A, dis[node], bq);
    float p = o.x * wq.x + o.y * wq.y + o.z * wq.z + o.w * wq.w;
    p += __shfl_xor(p, 1);
    p += __shfl_xor(p, 2);
    p += __shfl_xor(p, 4);
    if (sb == 0)
      atomicAdd(&gaccP[(node & (NCOPY - 1)) * N_GRAPHS + batch[node]], p);
  }
}

__global__ __launch_bounds__(256) void k_finalize(const float* __restrict__ gaccP,
                                                  const int* __restrict__ gcnt,
                                                  const float* __restrict__ bo,
                                                  float* __restrict__ out) {
  int g = blockIdx.x * 256 + threadIdx.x;
  if (g < N_GRAPHS) {
    float s = 0.f;
#pragma unroll 8
    for (int c = 0; c < NCOPY; ++c) s += gaccP[c * N_GRAPHS + g];
    out[g] = s / fmaxf((float)gcnt[g], 1.0f) + bo[0];
  }
}

// ---------------- launch ----------------

extern "C" void kernel_launch(void* const* d_in, const int* in_sizes, int n_in,
                              void* d_out, int out_size, void* d_ws, size_t ws_size,
                              hipStream_t stream) {
  const float* x     = (const float*)d_in[0];
  const int*   ei    = (const int*)d_in[1];   // [2, E]: src then dst
  const int*   batch = (const int*)d_in[2];
  const float* W1    = (const float*)d_in[3];
  const float* b1    = (const float*)d_in[4];
  const float* W2    = (const float*)d_in[5];
  const float* b2    = (const float*)d_in[6];
  const float* Wo    = (const float*)d_in[7];
  const float* bo    = (const float*)d_in[8];
  float* out = (float*)d_out;

  const int* src = ei;
  const int* dst = ei + N_EDGES;

  char* w = (char*)d_ws;
  float* gaccP   = (float*)w;  w += (size_t)NCOPY * N_GRAPHS * 4;   // zeroed
  size_t zero_bytes = (size_t)(w - (char*)d_ws);
  int*   gcnt    = (int*)w;    w += (size_t)N_GRAPHS * 4;
  int*   cnt     = (int*)w;    w += (size_t)ABLK * NBKT * 4;        // 2.05 MB
  int*   boff    = (int*)w;    w += (size_t)ABLK * NBKT * 4;        // 2.05 MB
  int*   btot    = (int*)w;    w += (size_t)(NBKT + 8) * 4;
  int*   bbase   = (int*)w;    w += (size_t)(NBKT + 8) * 4;
  u32*   binbuf  = (u32*)w;    w += (size_t)N_EDGES * 4;            // 6.4 MB (live through aggs)
  float* dis     = (float*)w;  w += (size_t)N_NODES * 4;
  u16*   hs1     = (u16*)w;    w += (size_t)(N_NODES + 1) * EMB * 2; // +1 zero row
  u16*   out1    = (u16*)w;    w += (size_t)N_NODES * EMB * 2;       // 6.4 MB
  u16*   hs2     = hs1;         // hs1 dead after agg1; zero row persists
  // total ~23.8 MB (< 25.8 MB layout that passed in R2)

  const int GB = (NTILE * 64 + 255) / 256;  // 1563 MFMA blocks

  (void)hipMemsetAsync(d_ws, 0, zero_bytes, stream);

  // bin pipeline: bucket histogram -> scans -> scatter (binbuf = src*100 + localdst)
  k_binA<<<ABLK, 256, 0, stream>>>(dst, cnt);
  k_binscanA<<<NBKT, 256, 0, stream>>>(cnt, boff, btot);
  k_binscanB<<<1, 256, 0, stream>>>(btot, bbase);
  k_binscat<<<ABLK, 256, 0, stream>>>(src, dst, boff, bbase, binbuf);
  k_deg_dis<<<NBKT, 256, 0, stream>>>(binbuf, bbase, dis, hs1);
  k_gcnt<<<1, 512, 0, stream>>>(batch, gcnt);

  k_gemm1<<<GB, 256, 0, stream>>>(x, W1, dis, hs1);
  k_agg1<<<NBKT, 256, 0, stream>>>(hs1, binbuf, bbase, dis, b1, out1);
  k_gemm2<<<GB, 256, 0, stream>>>(out1, W2, dis, hs2);
  k_agg2pool<<<NBKT, 256, 0, stream>>>(hs2, binbuf, bbase, dis, b2, Wo, batch, gaccP);
  k_finalize<<<2, 256, 0, stream>>>(gaccP, gcnt, bo, out);
}

// Round 5
// 232.989 us; speedup vs baseline: 3.1954x; 3.1954x over previous
//
#include <hip/hip_runtime.h>
#include <hip/hip_fp16.h>

#define N_NODES 100000
#define N_EDGES 1600000
#define N_GRAPHS 512
#define FEAT 128
#define EMB 32
#define ZROW N_NODES                        // dedicated zero row in hs table
#define NCOPY 64                            // privatized pool accumulator copies
#define NBKT 500                            // dst buckets
#define NPB 200                             // nodes per bucket
#define CAPB 4096                           // binbuf slots per bucket (avg 3200, 16-sigma safe)
#define COLCAP 5120                         // col slots per bucket (cnt + 7*NPB pad max ~4900)
#define ABLK 512                            // scatter blocks
#define EPB 3125                            // edges per scatter block
#define NTILE (N_NODES / 16)                // 6250 MFMA row tiles
#define AGB (N_NODES / 32)                  // 3125 agg blocks (32 nodes/block, 8/wave)

typedef unsigned short u16;
typedef unsigned int u32;
typedef _Float16 f16;
typedef float f32x4 __attribute__((ext_vector_type(4)));
typedef unsigned short u16x4 __attribute__((ext_vector_type(4)));
typedef f16 f16x8 __attribute__((ext_vector_type(8)));

__device__ __forceinline__ float4 h4_to_f4(u16x4 v) {
  union { unsigned int u; __half2 h; } a, b;
  a.u = (unsigned int)v.x | ((unsigned int)v.y << 16);
  b.u = (unsigned int)v.z | ((unsigned int)v.w << 16);
  float2 f0 = __half22float2(a.h);
  float2 f1 = __half22float2(b.h);
  return make_float4(f0.x, f0.y, f1.x, f1.y);
}

__device__ __forceinline__ u16x4 f4_to_h4(float4 f) {
  union { unsigned int u; __half2 h; } a, b;
  a.h = __float22half2_rn(make_float2(f.x, f.y));
  b.h = __float22half2_rn(make_float2(f.z, f.w));
  u16x4 r;
  r.x = (u16)(a.u & 0xffff); r.y = (u16)(a.u >> 16);
  r.z = (u16)(b.u & 0xffff); r.w = (u16)(b.u >> 16);
  return r;
}

__device__ __forceinline__ float4 relu_row(float4 acc, float d, float4 bq) {
  float4 o;
  o.x = fmaxf(fmaf(acc.x, d, bq.x), 0.f);
  o.y = fmaxf(fmaf(acc.y, d, bq.y), 0.f);
  o.z = fmaxf(fmaf(acc.z, d, bq.z), 0.f);
  o.w = fmaxf(fmaf(acc.w, d, bq.w), 0.f);
  return o;
}

// ---------------- k_scat: histogram + atomic block-reservation + scatter ----------------
// Replaces binA/binscanA/binscanB/binscat. Per-bucket fixed regions binbuf[b*CAPB..];
// global cur[b] holds final bucket counts afterward. ~500 global atomics per block
// (one per nonzero bucket, ~512 hits per counter total) -- contention trivial.

__global__ __launch_bounds__(256) void k_scat(const int* __restrict__ src,
                                              const int* __restrict__ dst,
                                              int* __restrict__ cur,
                                              u32* __restrict__ binbuf) {
  __shared__ int h[NBKT];
  __shared__ int posB[NBKT];
  int k = blockIdx.x, t = threadIdx.x;
  for (int i = t; i < NBKT; i += 256) h[i] = 0;
  __syncthreads();
  int e0 = k * EPB;
  int e1 = min(e0 + EPB, N_EDGES);
  for (int e = e0 + t; e < e1; e += 256)
    atomicAdd(&h[(u32)dst[e] / (u32)NPB], 1);
  __syncthreads();
  for (int i = t; i < NBKT; i += 256) {
    int c = h[i];
    posB[i] = c ? atomicAdd(&cur[i], c) : 0;
    h[i] = 0;                               // reuse as local cursor
  }
  __syncthreads();
  for (int e = e0 + t; e < e1; e += 256) {
    u32 d = (u32)dst[e];
    int b = d / (u32)NPB;
    int r = atomicAdd(&h[b], 1);
    binbuf[(size_t)b * CAPB + posB[b] + r] = (u32)src[e] * (u32)NPB + (d - (u32)b * NPB);
  }
}

// ---------------- k_build: per-bucket CSR (hist + LDS scan + scatter + pad) ----------------
// Replaces bdeg/node_init/scanA/scanB/scanC/fillB. Per-bucket col base b*COLCAP
// removes the global pad8 prefix scan. rowinfo[node] = (abs col start, pad8 deg).
// Also writes dis = rsqrt(deg+1) and zeroes the hs ZROW (block 0).

__global__ __launch_bounds__(256) void k_build(const u32* __restrict__ binbuf,
                                               const int* __restrict__ cur,
                                               int* __restrict__ col,
                                               int2* __restrict__ rowinfo,
                                               float* __restrict__ dis,
                                               u16* __restrict__ hs1) {
  __shared__ int c[NPB];     // histogram, then scatter cursor
  __shared__ int sc[256];    // scan workspace
  __shared__ int rpl[NPB];   // exclusive scan of pad8(deg)
  int b = blockIdx.x, t = threadIdx.x;
  int cnt = cur[b];
  const u32* eb = binbuf + (size_t)b * CAPB;
  for (int i = t; i < NPB; i += 256) c[i] = 0;
  __syncthreads();
  for (int i = t; i < cnt; i += 256) {
    u32 p = eb[i];
    u32 s = p / (u32)NPB;
    atomicAdd(&c[p - s * (u32)NPB], 1);
  }
  __syncthreads();
  int deg = (t < NPB) ? c[t] : 0;
  int p8 = (deg + 7) & ~7;
  sc[t] = p8;
  __syncthreads();
  for (int o = 1; o < 256; o <<= 1) {
    int add = (t >= o) ? sc[t - o] : 0;
    __syncthreads();
    sc[t] += add;
    __syncthreads();
  }
  int colbase = b * COLCAP;
  if (t < NPB) {
    int rp = sc[t] - p8;
    rpl[t] = rp;
    int node = b * NPB + t;
    rowinfo[node] = make_int2(colbase + rp, p8);
    dis[node] = rsqrtf((float)deg + 1.0f);
    for (int j = deg; j < p8; j++) col[colbase + rp + j] = ZROW;  // pad slots
    c[t] = 0;                                                     // reset as cursor
  }
  __syncthreads();
  for (int i = t; i < cnt; i += 256) {
    u32 p = eb[i];
    u32 s = p / (u32)NPB;
    int ld = (int)(p - s * (u32)NPB);
    int pos = atomicAdd(&c[ld], 1);
    col[colbase + rpl[ld] + pos] = (int)s;
  }
  if (b == 0)
    for (int i = t; i < EMB; i += 256) hs1[(size_t)ZROW * EMB + i] = 0;
}

// ---------------- GEMMs via MFMA 16x16x32 f16 (W in register B-frags) ----------------

__global__ __launch_bounds__(256) void k_gemm1(const float* __restrict__ x,
                                               const float* __restrict__ W1,
                                               const float* __restrict__ dis,
                                               u16* __restrict__ hs1) {
  int wid = (blockIdx.x * 256 + threadIdx.x) >> 6;   // wave id = 16-row tile
  if (wid >= NTILE) return;
  int l = threadIdx.x & 63;
  int m = l & 15, q = l >> 4;
  f16x8 B[4][2];
#pragma unroll
  for (int s = 0; s < 4; ++s)
#pragma unroll
    for (int h = 0; h < 2; ++h)
#pragma unroll
      for (int j = 0; j < 8; ++j)
        B[s][h][j] = (f16)W1[(s * 32 + q * 8 + j) * EMB + h * 16 + m];
  int row = wid * 16 + m;
  const float* xr = x + (size_t)row * FEAT + q * 8;
  f32x4 acc0 = {0.f, 0.f, 0.f, 0.f}, acc1 = {0.f, 0.f, 0.f, 0.f};
#pragma unroll
  for (int s = 0; s < 4; ++s) {
    f32x4 xa = __builtin_nontemporal_load((const f32x4*)(xr + s * 32));
    f32x4 xb = __builtin_nontemporal_load((const f32x4*)(xr + s * 32 + 4));
    f16x8 A;
    A[0] = (f16)xa.x; A[1] = (f16)xa.y; A[2] = (f16)xa.z; A[3] = (f16)xa.w;
    A[4] = (f16)xb.x; A[5] = (f16)xb.y; A[6] = (f16)xb.z; A[7] = (f16)xb.w;
    acc0 = __builtin_amdgcn_mfma_f32_16x16x32_f16(A, B[s][0], acc0, 0, 0, 0);
    acc1 = __builtin_amdgcn_mfma_f32_16x16x32_f16(A, B[s][1], acc1, 0, 0, 0);
  }
  f32x4 dq = *(const f32x4*)(dis + wid * 16 + q * 4);
  u16* o = hs1 + (size_t)(wid * 16) * EMB;
#pragma unroll
  for (int i = 0; i < 4; ++i) {
    int r = q * 4 + i;
    float dv = (i == 0) ? dq.x : (i == 1) ? dq.y : (i == 2) ? dq.z : dq.w;
    o[(size_t)r * EMB + m]      = __half_as_ushort(__float2half_rn(acc0[i] * dv));
    o[(size_t)r * EMB + 16 + m] = __half_as_ushort(__float2half_rn(acc1[i] * dv));
  }
}

__global__ __launch_bounds__(256) void k_gemm2(const u16* __restrict__ in1,
                                               const float* __restrict__ W2,
                                               const float* __restrict__ dis,
                                               u16* __restrict__ hs2) {
  int wid = (blockIdx.x * 256 + threadIdx.x) >> 6;
  if (wid >= NTILE) return;
  int l = threadIdx.x & 63;
  int m = l & 15, q = l >> 4;
  f16x8 B[2];
#pragma unroll
  for (int h = 0; h < 2; ++h)
#pragma unroll
    for (int j = 0; j < 8; ++j)
      B[h][j] = (f16)W2[(q * 8 + j) * EMB + h * 16 + m];
  int row = wid * 16 + m;
  f16x8 A = *(const f16x8*)(in1 + (size_t)row * EMB + q * 8);
  f32x4 acc0 = {0.f, 0.f, 0.f, 0.f}, acc1 = {0.f, 0.f, 0.f, 0.f};
  acc0 = __builtin_amdgcn_mfma_f32_16x16x32_f16(A, B[0], acc0, 0, 0, 0);
  acc1 = __builtin_amdgcn_mfma_f32_16x16x32_f16(A, B[1], acc1, 0, 0, 0);
  f32x4 dq = *(const f32x4*)(dis + wid * 16 + q * 4);
  u16* o = hs2 + (size_t)(wid * 16) * EMB;
#pragma unroll
  for (int i = 0; i < 4; ++i) {
    int r = q * 4 + i;
    float dv = (i == 0) ? dq.x : (i == 1) ? dq.y : (i == 2) ? dq.z : dq.w;
    o[(size_t)r * EMB + m]      = __half_as_ushort(__float2half_rn(acc0[i] * dv));
    o[(size_t)r * EMB + 16 + m] = __half_as_ushort(__float2half_rn(acc1[i] * dv));
  }
}

// ---------------- Aggregation: 8 lanes per node, shuffle-free, deep-pipelined ----------------
// R2-proven structure (best agg measured: ~1.5 TB/s effective). 8 nodes per wave
// (8 lanes/node, sub=l&7 owns 4 dims). Lane walks its node's padded slot list 8 at a
// time (pad8 -> ZROW-padded full blocks, no per-slot bounds checks), 8 gathers + int4
// col prefetch in flight. rowinfo int2 = single 8B load for (start, padded-len).

__device__ __forceinline__ void acc4(float4& A, u16x4 v) {
  float4 f = h4_to_f4(v);
  A.x += f.x; A.y += f.y; A.z += f.z; A.w += f.w;
}

__device__ __forceinline__ float4 agg_node(const u16* __restrict__ hs,
                                           const int2* __restrict__ rowinfo,
                                           const int* __restrict__ col,
                                           int node, int sub) {
  const u16x4* t4 = (const u16x4*)hs;
  int2 ri = rowinfo[node];
  int a0 = ri.x, na = ri.y;                 // pad8 degree; a0 8-slot aligned
  const int* cp = col + a0;
  int4 c0 = *(const int4*)cp;               // slots 0..3 (in-bounds even if na==0)
  int4 c1 = *(const int4*)(cp + 4);         // slots 4..7
  float4 A = make_float4(0.f, 0.f, 0.f, 0.f);
  for (int i = 0; i < na; i += 8) {
    u16x4 v0 = t4[(size_t)c0.x * 8 + sub];
    u16x4 v1 = t4[(size_t)c0.y * 8 + sub];
    u16x4 v2 = t4[(size_t)c0.z * 8 + sub];
    u16x4 v3 = t4[(size_t)c0.w * 8 + sub];
    u16x4 v4 = t4[(size_t)c1.x * 8 + sub];
    u16x4 v5 = t4[(size_t)c1.y * 8 + sub];
    u16x4 v6 = t4[(size_t)c1.z * 8 + sub];
    u16x4 v7 = t4[(size_t)c1.w * 8 + sub];
    if (i + 8 < na) {                       // prefetch next col block
      c0 = *(const int4*)(cp + i + 8);
      c1 = *(const int4*)(cp + i + 12);
    }
    acc4(A, v0); acc4(A, v1); acc4(A, v2); acc4(A, v3);
    acc4(A, v4); acc4(A, v5); acc4(A, v6); acc4(A, v7);
  }
  // self-loop contribution (row pre-scaled by dis[node] at GEMM time)
  acc4(A, t4[(size_t)node * 8 + sub]);
  return A;
}

// grid = N_NODES/32 blocks; wave handles 8 nodes, lane group (l>>3) one node
__global__ __launch_bounds__(256) void k_agg1(const u16* __restrict__ hs,
                                              const int2* __restrict__ rowinfo,
                                              const int* __restrict__ col,
                                              const float* __restrict__ dis,
                                              const float* __restrict__ b,
                                              u16* __restrict__ out) {
  int t = threadIdx.x;
  int l = t & 63;
  int node = blockIdx.x * 32 + (t >> 6) * 8 + (l >> 3);
  int sub = l & 7;
  float4 A = agg_node(hs, rowinfo, col, node, sub);
  float4 bq = ((const float4*)b)[sub];
  float4 o = relu_row(A, dis[node], bq);
  ((u16x4*)(out + (size_t)node * EMB))[sub] = f4_to_h4(o);
}

__global__ __launch_bounds__(256) void k_agg2pool(const u16* __restrict__ hs,
                                                  const int2* __restrict__ rowinfo,
                                                  const int* __restrict__ col,
                                                  const float* __restrict__ dis,
                                                  const float* __restrict__ b2,
                                                  const float* __restrict__ Wo,
                                                  const int* __restrict__ batch,
                                                  float* __restrict__ gaccP) {
  int t = threadIdx.x;
  int l = t & 63;
  int node = blockIdx.x * 32 + (t >> 6) * 8 + (l >> 3);
  int sub = l & 7;
  float4 A = agg_node(hs, rowinfo, col, node, sub);
  float4 bq = ((const float4*)b2)[sub];
  float4 wq = ((const float4*)Wo)[sub];
  float4 o = relu_row(A, dis[node], bq);
  float p = o.x * wq.x + o.y * wq.y + o.z * wq.z + o.w * wq.w;
  p += __shfl_xor(p, 1);
  p += __shfl_xor(p, 2);
  p += __shfl_xor(p, 4);
  if (sub == 0)
    atomicAdd(&gaccP[(node & (NCOPY - 1)) * N_GRAPHS + batch[node]], p);
}

// finalize (absorbs k_gcnt: per-graph node count via binary search on sorted batch)
__global__ __launch_bounds__(256) void k_finalize(const float* __restrict__ gaccP,
                                                  const int* __restrict__ batch,
                                                  const float* __restrict__ bo,
                                                  float* __restrict__ out) {
  int g = blockIdx.x * 256 + threadIdx.x;
  if (g < N_GRAPHS) {
    int lo = 0, hi = N_NODES;
    while (lo < hi) { int mid = (lo + hi) >> 1; if (batch[mid] < g) lo = mid + 1; else hi = mid; }
    int lo1 = lo; hi = N_NODES;
    while (lo < hi) { int mid = (lo + hi) >> 1; if (batch[mid] < g + 1) lo = mid + 1; else hi = mid; }
    int cntg = lo - lo1;
    float s = 0.f;
#pragma unroll 8
    for (int c = 0; c < NCOPY; ++c) s += gaccP[c * N_GRAPHS + g];
    out[g] = s / fmaxf((float)cntg, 1.0f) + bo[0];
  }
}

// ---------------- launch ----------------

extern "C" void kernel_launch(void* const* d_in, const int* in_sizes, int n_in,
                              void* d_out, int out_size, void* d_ws, size_t ws_size,
                              hipStream_t stream) {
  const float* x     = (const float*)d_in[0];
  const int*   ei    = (const int*)d_in[1];   // [2, E]: src then dst
  const int*   batch = (const int*)d_in[2];
  const float* W1    = (const float*)d_in[3];
  const float* b1    = (const float*)d_in[4];
  const float* W2    = (const float*)d_in[5];
  const float* b2    = (const float*)d_in[6];
  const float* Wo    = (const float*)d_in[7];
  const float* bo    = (const float*)d_in[8];
  float* out = (float*)d_out;

  const int* src = ei;
  const int* dst = ei + N_EDGES;

  char* w = (char*)d_ws;
  float* gaccP   = (float*)w;  w += (size_t)NCOPY * N_GRAPHS * 4;     // zeroed
  int*   cur     = (int*)w;    w += (size_t)(NBKT + 8) * 4;           // zeroed
  size_t zero_bytes = (size_t)(w - (char*)d_ws);
  u32*   binbuf  = (u32*)w;    w += (size_t)NBKT * CAPB * 4;          // 8.2 MB
  int*   col     = (int*)w;    w += ((size_t)NBKT * COLCAP + 64) * 4; // 10.2 MB
  int2*  rowinfo = (int2*)w;   w += (size_t)(N_NODES + 8) * 8;        // 800 KB
  float* dis     = (float*)w;  w += (size_t)N_NODES * 4;
  u16*   hs1     = (u16*)w;    w += (size_t)(N_NODES + 1) * EMB * 2;  // +1 zero row
  u16*   out1    = (u16*)w;    w += (size_t)N_NODES * EMB * 2;        // 6.4 MB
  u16*   hs2     = hs1;        // hs1 dead after agg1; zero row persists
  // total ~33 MB (workspace is 256 MB per harness fill)

  const int GB = (NTILE * 64 + 255) / 256;  // 1563 MFMA blocks

  (void)hipMemsetAsync(d_ws, 0, zero_bytes, stream);

  k_scat<<<ABLK, 256, 0, stream>>>(src, dst, cur, binbuf);
  k_build<<<NBKT, 256, 0, stream>>>(binbuf, cur, col, rowinfo, dis, hs1);
  k_gemm1<<<GB, 256, 0, stream>>>(x, W1, dis, hs1);
  k_agg1<<<AGB, 256, 0, stream>>>(hs1, rowinfo, col, dis, b1, out1);
  k_gemm2<<<GB, 256, 0, stream>>>(out1, W2, dis, hs2);
  k_agg2pool<<<AGB, 256, 0, stream>>>(hs2, rowinfo, col, dis, b2, Wo, batch, gaccP);
  k_finalize<<<2, 256, 0, stream>>>(gaccP, batch, bo, out);
}